// Round 9
// baseline (217.834 us; speedup 1.0000x reference)
//
#include <hip/hip_runtime.h>
#include <math.h>

// ---------- types ----------
typedef __attribute__((ext_vector_type(4)))  float f32x4;
typedef __attribute__((ext_vector_type(16))) float f32x16;
typedef __attribute__((ext_vector_type(8)))  short bf16x8;   // 8 bf16 in 4 VGPRs
typedef __attribute__((ext_vector_type(4)))  short s16x4;

#define SQUISH_U 1.8137993642342178f      // pi/sqrt(3)  (applied to u = sp(z)/ln2)
#define LN2F     0.69314718055994531f

__device__ __forceinline__ float b2f(short u) {
    union { float f; unsigned b; } v; v.b = ((unsigned)(unsigned short)u) << 16; return v.f;
}
__device__ __forceinline__ short f2b(float f) {
    union { float f; unsigned b; } v; v.f = f;
    unsigned r = (v.b + 0x7FFFu + ((v.b >> 16) & 1u)) >> 16;   // RNE
    return (short)r;
}
__device__ __forceinline__ unsigned cvt_pk_bf16(float lo, float hi) {
    unsigned r;
    asm("v_cvt_pk_bf16_f32 %0, %1, %2" : "=v"(r) : "v"(lo), "v"(hi));
    return r;
}
// async global->LDS; lds base wave-uniform, HW adds lane*size
__device__ __forceinline__ void gll16(const void* g, void* l) {
    __builtin_amdgcn_global_load_lds((const __attribute__((address_space(1))) void*)g,
                                     (__attribute__((address_space(3))) void*)l, 16, 0, 0);
}
__device__ __forceinline__ void gll4(const void* g, void* l) {
    __builtin_amdgcn_global_load_lds((const __attribute__((address_space(1))) void*)g,
                                     (__attribute__((address_space(3))) void*)l, 4, 0, 0);
}

// ---------- unified prep kernel ----------
__device__ __forceinline__ void do_transpose(const float* __restrict__ src, int R, int C,
                                             short* __restrict__ dst, float scale,
                                             int c0, int r0, float (*tile)[65], int tid) {
    #pragma unroll
    for (int it = 0; it < 4; ++it) {
        int lin = it * 256 + tid;
        int r = lin >> 4, c4 = lin & 15;
        f32x4 v = *(const f32x4*)(src + (size_t)(r0 + r) * C + c0 + c4 * 4);
        #pragma unroll
        for (int k = 0; k < 4; ++k) tile[r][c4 * 4 + k] = v[k];
    }
    __syncthreads();
    #pragma unroll
    for (int it = 0; it < 4; ++it) {
        int lin = it * 256 + tid;
        int c = lin >> 4, rq = lin & 15;
        s16x4 o;
        #pragma unroll
        for (int k = 0; k < 4; ++k) o[k] = f2b(tile[rq * 4 + k][c] * scale);
        *(s16x4*)(dst + (size_t)(c0 + c) * R + r0 + rq * 4) = o;
    }
}

__global__ __launch_bounds__(256) void prep_kernel(
    const float* __restrict__ X, const float* __restrict__ W_Q, const float* __restrict__ W_K,
    const float* __restrict__ W_V, const float* __restrict__ W_O,
    const float* __restrict__ bQ, const float* __restrict__ bK, const float* __restrict__ bV,
    const float* __restrict__ bO,
    short* __restrict__ Xb, short* __restrict__ WbT, short* __restrict__ WoT,
    float* __restrict__ biasQKV, float* __restrict__ out) {
    __shared__ float tile[64][65];
    const int bid = blockIdx.x, tid = threadIdx.x;
    if (bid < 256) {
        int i = (bid * 256 + tid) * 16;
        #pragma unroll
        for (int k = 0; k < 4; ++k) {
            f32x4 v = *(const f32x4*)(X + i + k * 4);
            s16x4 o;
            o.x = f2b(v.x); o.y = f2b(v.y); o.z = f2b(v.z); o.w = f2b(v.w);
            *(s16x4*)(Xb + i + k * 4) = o;
        }
    } else if (bid < 1280) {
        int b2 = bid - 256;
        do_transpose(W_Q, 1024, 4096, WbT, 1.f, (b2 & 63) * 64, (b2 >> 6) * 64, tile, tid);
    } else if (bid < 1536) {
        int b2 = bid - 1280;
        do_transpose(W_K, 1024, 1024, WbT + 4096 * 1024, 1.f, (b2 & 15) * 64, (b2 >> 4) * 64, tile, tid);
    } else if (bid < 1792) {
        int b2 = bid - 1536;
        do_transpose(W_V, 1024, 1024, WbT + 5120 * 1024, 1.f, (b2 & 15) * 64, (b2 >> 4) * 64, tile, tid);
    } else if (bid < 2816) {
        int b2 = bid - 1792;
        do_transpose(W_O, 4096, 1024, WoT, 0.25f, (b2 & 15) * 64, (b2 >> 4) * 64, tile, tid);
    } else if (bid < 2840) {
        int i = (bid - 2816) * 256 + tid;
        if (i < 4096)      biasQKV[i] = bQ[i];
        else if (i < 5120) biasQKV[i] = bK[i - 4096];
        else               biasQKV[i] = bV[i - 5120];
    } else {
        int i = ((bid - 2840) * 256 + tid) * 4;
        f32x4 v;
        #pragma unroll
        for (int k = 0; k < 4; ++k) {
            int c = (i + k) & 1023;
            v[k] = 0.25f * (bO[c] + bO[1024 + c] + bO[2048 + c] + bO[3072 + c]);
        }
        *(f32x4*)(out + i) = v;
    }
}

// ---------- 64x128 GEMM core, dbuf counted-vmcnt (16x16x32 MFMA) ----------
#define GSTAGE_64x128(k0_, b_) do {                                            \
    _Pragma("unroll")                                                          \
    for (int it = 0; it < 2; ++it) {                                           \
        int lin0 = it * 256 + wave * 64;                                       \
        int lin = lin0 + lane;                                                 \
        int r = lin >> 3, c = (lin & 7) ^ (r & 7);                             \
        gll16(A + (size_t)(m0 + r) * K + (k0_) + c * 8, (char*)lA[b_] + lin0 * 16); \
    }                                                                          \
    _Pragma("unroll")                                                          \
    for (int it = 0; it < 4; ++it) {                                           \
        int lin0 = it * 256 + wave * 64;                                       \
        int lin = lin0 + lane;                                                 \
        int r = lin >> 3, c = (lin & 7) ^ (r & 7);                             \
        gll16(BT + (size_t)(n0 + r) * K + (k0_) + c * 8, (char*)lB[b_] + lin0 * 16); \
    } } while (0)

#define GEMM_CORE_64x128(kbeg_, kend_)                                         \
    GSTAGE_64x128(kbeg_, 0);                                                   \
    int cur = 0;                                                               \
    for (int k0 = (kbeg_); k0 < (kend_); k0 += 64) {                           \
        if (k0 + 64 < (kend_)) {                                               \
            GSTAGE_64x128(k0 + 64, cur ^ 1);                                   \
            asm volatile("s_waitcnt vmcnt(6) lgkmcnt(0)" ::: "memory");        \
        } else {                                                               \
            asm volatile("s_waitcnt vmcnt(0) lgkmcnt(0)" ::: "memory");        \
        }                                                                      \
        __builtin_amdgcn_s_barrier();                                          \
        _Pragma("unroll")                                                      \
        for (int kk = 0; kk < 2; ++kk) {                                       \
            bf16x8 af[2], bf_[4];                                              \
            _Pragma("unroll")                                                  \
            for (int m = 0; m < 2; ++m) {                                      \
                int row = wr * 32 + m * 16 + l15;                              \
                int ch = (kk * 4 + l4) ^ (row & 7);                            \
                af[m] = *(const bf16x8*)&lA[cur][row][ch << 3];                \
            }                                                                  \
            _Pragma("unroll")                                                  \
            for (int n = 0; n < 4; ++n) {                                      \
                int row = wc * 64 + n * 16 + l15;                              \
                int ch = (kk * 4 + l4) ^ (row & 7);                            \
                bf_[n] = *(const bf16x8*)&lB[cur][row][ch << 3];               \
            }                                                                  \
            _Pragma("unroll")                                                  \
            for (int m = 0; m < 2; ++m)                                        \
                _Pragma("unroll")                                              \
                for (int n = 0; n < 4; ++n)                                    \
                    acc[m][n] = __builtin_amdgcn_mfma_f32_16x16x32_bf16(af[m], bf_[n], acc[m][n], 0, 0, 0); \
        }                                                                      \
        asm volatile("" ::: "memory");                                         \
        __builtin_amdgcn_s_barrier();                                          \
        cur ^= 1;                                                              \
    }

// ---------- QKV GEMM with fused bias + RoPE + ksr + V-transpose ----------
__global__ __launch_bounds__(256, 3) void gemm_qkvf_kernel(
    const short* __restrict__ A, const short* __restrict__ BT,
    const float* __restrict__ bias, short* __restrict__ QKVb,
    short* __restrict__ Vtb, float* __restrict__ ksr,
    int M, int N, int K) {
    __shared__ short lA[2][64][64];
    __shared__ short lB[2][128][64];
    const int tid = threadIdx.x;
    const int lane = tid & 63, wave = tid >> 6;
    const int l15 = lane & 15, l4 = lane >> 4;
    const int wr = wave >> 1, wc = wave & 1;
    const int n0 = blockIdx.x * 128, m0 = blockIdx.y * 64;

    f32x4 acc[2][4];
    const f32x4 fz = {0.f, 0.f, 0.f, 0.f};
    #pragma unroll
    for (int m = 0; m < 2; ++m)
        #pragma unroll
        for (int n = 0; n < 4; ++n) acc[m][n] = fz;

    GEMM_CORE_64x128(0, K);

    const int head = blockIdx.x * 2 + wc;
    float bn[4];
    #pragma unroll
    for (int n = 0; n < 4; ++n) bn[n] = bias[head * 64 + n * 16 + l15];
    #pragma unroll
    for (int m = 0; m < 2; ++m)
        #pragma unroll
        for (int n = 0; n < 4; ++n)
            #pragma unroll
            for (int r = 0; r < 4; ++r) acc[m][n][r] += bn[n];

    if (head < 80) {
        // RoPE applied on fp32 acc
        const float invf0 = __builtin_exp2f(-(float)l15 * 0.41524101186092033f); // 10000^(-l15/32)
        const float invf1 = invf0 * 0.01f;
        const int p1 = (2 * l15) & 15, p2 = (2 * l15 + 1) & 15;
        #pragma unroll
        for (int m = 0; m < 2; ++m) {
            int tb = m0 + wr * 32 + m * 16 + l4 * 4;
            float x1lo[4], x2lo[4], x1hi[4], x2hi[4];
            #pragma unroll
            for (int r = 0; r < 4; ++r) {
                float a0 = __shfl(acc[m][0][r], p1, 16), b0 = __shfl(acc[m][1][r], p1, 16);
                float a1 = __shfl(acc[m][0][r], p2, 16), b1 = __shfl(acc[m][1][r], p2, 16);
                x1lo[r] = (l15 < 8) ? a0 : b0;
                x2lo[r] = (l15 < 8) ? a1 : b1;
                float c0 = __shfl(acc[m][2][r], p1, 16), d0 = __shfl(acc[m][3][r], p1, 16);
                float c1 = __shfl(acc[m][2][r], p2, 16), d1 = __shfl(acc[m][3][r], p2, 16);
                x1hi[r] = (l15 < 8) ? c0 : d0;
                x2hi[r] = (l15 < 8) ? c1 : d1;
            }
            #pragma unroll
            for (int r = 0; r < 4; ++r) {
                float tf = (float)(tb + r);
                float f0 = tf * invf0, f1 = tf * invf1;
                float s0 = __sinf(f0), c0 = __cosf(f0);
                float s1 = __sinf(f1), c1 = __cosf(f1);
                acc[m][0][r] = x1lo[r] * c0 - x2lo[r] * s0;
                acc[m][2][r] = x1lo[r] * s0 + x2lo[r] * c0;
                acc[m][1][r] = x1hi[r] * c1 - x2hi[r] * s1;
                acc[m][3][r] = x1hi[r] * s1 + x2hi[r] * c1;
            }
        }
    }

    if (head >= 80) {
        const int h16 = head - 80;
        #pragma unroll
        for (int m = 0; m < 2; ++m) {
            int tb = m0 + wr * 32 + m * 16 + l4 * 4;
            #pragma unroll
            for (int n = 0; n < 4; ++n) {
                s16x4 o;
                #pragma unroll
                for (int r = 0; r < 4; ++r) o[r] = f2b(acc[m][n][r]);
                *(s16x4*)(Vtb + (size_t)(h16 * 64 + n * 16 + l15) * 1024 + tb) = o;
            }
        }
    } else {
        const size_t coff = (head < 64) ? (size_t)head * 64 : (size_t)(4096 + (head - 64) * 64);
        #pragma unroll
        for (int m = 0; m < 2; ++m)
            #pragma unroll
            for (int r = 0; r < 4; ++r) {
                int row = m0 + wr * 32 + m * 16 + l4 * 4 + r;
                #pragma unroll
                for (int n = 0; n < 4; ++n)
                    QKVb[(size_t)row * 6144 + coff + n * 16 + l15] = f2b(acc[m][n][r]);
            }
        if (head >= 64) {
            const int h16 = head - 64;
            #pragma unroll
            for (int m = 0; m < 2; ++m)
                #pragma unroll
                for (int r = 0; r < 4; ++r) {
                    float ss = 0.f;
                    #pragma unroll
                    for (int n = 0; n < 4; ++n) ss += acc[m][n][r] * acc[m][n][r];
                    ss += __shfl_xor(ss, 1, 16);
                    ss += __shfl_xor(ss, 2, 16);
                    ss += __shfl_xor(ss, 4, 16);
                    ss += __shfl_xor(ss, 8, 16);
                    if (l15 == 0)
                        ksr[h16 * 1024 + m0 + wr * 32 + m * 16 + l4 * 4 + r] =
                            0.18033688011112042f * rsqrtf(fmaxf(ss, 1e-6f));   // log2e * 0.125 * rsqrt
                }
        }
    }
}

// ---------- out-proj: 128x128 tile, 32x32x16 MFMA, split-K=8, fp32 atomic acc ----------
__global__ __launch_bounds__(256, 2) void gemm_op_kernel(
    const short* __restrict__ A, const short* __restrict__ BT,
    float* __restrict__ out, int M, int N, int K, int KSLICE) {
    __shared__ short lA[2][128][64];
    __shared__ short lB[2][128][64];
    const int tid = threadIdx.x;
    const int lane = tid & 63, wave = tid >> 6;
    const int l31 = lane & 31, l5 = lane >> 5;
    const int wr = wave >> 1, wc = wave & 1;
    const int n0 = blockIdx.x * 128, m0 = blockIdx.y * 128;
    const int kbeg = blockIdx.z * KSLICE, kend = kbeg + KSLICE;

    f32x16 acc[2][2];
    #pragma unroll
    for (int m = 0; m < 2; ++m)
        #pragma unroll
        for (int n = 0; n < 2; ++n)
            #pragma unroll
            for (int g = 0; g < 16; ++g) acc[m][n][g] = 0.f;

#define GSTAGE_128(k0_, b_) do {                                               \
    _Pragma("unroll")                                                          \
    for (int it = 0; it < 4; ++it) {                                           \
        int lin0 = it * 256 + wave * 64;                                       \
        int lin = lin0 + lane;                                                 \
        int r = lin >> 3, c = (lin & 7) ^ (r & 7);                             \
        gll16(A  + (size_t)(m0 + r) * K + (k0_) + c * 8, (char*)lA[b_] + lin0 * 16); \
        gll16(BT + (size_t)(n0 + r) * K + (k0_) + c * 8, (char*)lB[b_] + lin0 * 16); \
    } } while (0)

    GSTAGE_128(kbeg, 0);
    int cur = 0;
    for (int k0 = kbeg; k0 < kend; k0 += 64) {
        if (k0 + 64 < kend) {
            GSTAGE_128(k0 + 64, cur ^ 1);
            asm volatile("s_waitcnt vmcnt(8) lgkmcnt(0)" ::: "memory");
        } else {
            asm volatile("s_waitcnt vmcnt(0) lgkmcnt(0)" ::: "memory");
        }
        __builtin_amdgcn_s_barrier();
        // 4 k-steps of 16; logical chunk q = kk*2 + l5, swizzled by row
        #pragma unroll
        for (int kk = 0; kk < 2; ++kk) {
            bf16x8 af[2], bf_[2];
            #pragma unroll
            for (int m = 0; m < 2; ++m) {
                int row = wr * 64 + m * 32 + l31;
                int ch = (kk * 2 + l5) ^ (row & 7);
                af[m] = *(const bf16x8*)&lA[cur][row][ch << 3];
            }
            #pragma unroll
            for (int n = 0; n < 2; ++n) {
                int row = wc * 64 + n * 32 + l31;
                int ch = (kk * 2 + l5) ^ (row & 7);
                bf_[n] = *(const bf16x8*)&lB[cur][row][ch << 3];
            }
            // each bf16x8 covers K=16 at k = kk*16 + l5*8 -> one 32x32x16 MFMA
            #pragma unroll
            for (int m = 0; m < 2; ++m)
                #pragma unroll
                for (int n = 0; n < 2; ++n)
                    acc[m][n] = __builtin_amdgcn_mfma_f32_32x32x16_bf16(af[m], bf_[n], acc[m][n], 0, 0, 0);
            // second pair of k-chunks (q = 4 + kk*2 + l5)
            #pragma unroll
            for (int m = 0; m < 2; ++m) {
                int row = wr * 64 + m * 32 + l31;
                int ch = (4 + kk * 2 + l5) ^ (row & 7);
                af[m] = *(const bf16x8*)&lA[cur][row][ch << 3];
            }
            #pragma unroll
            for (int n = 0; n < 2; ++n) {
                int row = wc * 64 + n * 32 + l31;
                int ch = (4 + kk * 2 + l5) ^ (row & 7);
                bf_[n] = *(const bf16x8*)&lB[cur][row][ch << 3];
            }
            #pragma unroll
            for (int m = 0; m < 2; ++m)
                #pragma unroll
                for (int n = 0; n < 2; ++n)
                    acc[m][n] = __builtin_amdgcn_mfma_f32_32x32x16_bf16(af[m], bf_[n], acc[m][n], 0, 0, 0);
        }
        asm volatile("" ::: "memory");
        __builtin_amdgcn_s_barrier();
        cur ^= 1;
    }
#undef GSTAGE_128
    // C/D layout 32x32: col = lane&31, row = (g&3) + 8*(g>>2) + 4*(lane>>5)
    #pragma unroll
    for (int m = 0; m < 2; ++m)
        #pragma unroll
        for (int n = 0; n < 2; ++n)
            #pragma unroll
            for (int g = 0; g < 16; ++g) {
                int row = m0 + wr * 64 + m * 32 + (g & 3) + 8 * (g >> 2) + 4 * l5;
                int col = n0 + wc * 64 + n * 32 + l31;
                unsafeAtomicAdd(&out[(size_t)row * N + col], acc[m][n][g]);
            }
}

// ---------- attention, k-split + T14 reg-prefetch ----------
__constant__ __device__ const signed char TQT[24] = {15,15,14, 7,14,13,13,12, 6,12,11,11,10, 5,10, 9, 9, 8, 4, 8, 3, 2, 1, 0};
__constant__ __device__ const signed char TKB[24] = { 0, 8, 0, 0, 8, 0, 7, 0, 0, 7, 0, 6, 0, 0, 6, 0, 5, 0, 0, 5, 0, 0, 0, 0};
__constant__ __device__ const signed char TKE[24] = { 8,16, 8, 8,15, 7,14, 7, 7,13, 6,12, 6, 6,11, 5,10, 5, 5, 9, 4, 3, 2, 1};

__global__ __launch_bounds__(256, 6) void attn_kernel(
    const short* __restrict__ QKVb, const short* __restrict__ Vtb,
    const float* __restrict__ ksr, const float* __restrict__ sinks,
    const float* __restrict__ vnulls, short* __restrict__ Ob,
    float* __restrict__ Of0, float* __restrict__ Of1,
    float* __restrict__ tot0, float* __restrict__ tot1) {
    __shared__ short lK[64][64];
    __shared__ short lV[64][64];
    __shared__ float lks[64];
    __shared__ float lvn[64];
    __shared__ short lP[4][16][64];

    const int tid = threadIdx.x;
    const int lane = tid & 63, wave = tid >> 6;
    const int l15 = lane & 15, l4 = lane >> 4;
    const int h = blockIdx.x;
    const int slot = blockIdx.y;
    const int qt = TQT[slot], kb = TKB[slot], ke = TKE[slot];
    const bool single = (kb == 0) && (ke == qt + 1);
    const int h16 = h & 15;
    const int t0 = qt * 64;
    const float sink = sinks[h];
    if (tid < 64) lvn[tid] = vnulls[h * 64 + tid];

    const int q_abs = t0 + wave * 16 + l15;
    bf16x8 aq[2];
    #pragma unroll
    for (int kk = 0; kk < 2; ++kk)
        aq[kk] = *(const bf16x8*)(QKVb + (size_t)q_abs * 6144 + h * 64 + kk * 32 + l4 * 8);

    const f32x4 fz = {0.f, 0.f, 0.f, 0.f};
    f32x4 acc_o[4];
    #pragma unroll
    for (int n = 0; n < 4; ++n) acc_o[n] = fz;
    float tot = 0.f;

    // prefetch address components (pre-swizzled; match gll16's linear-dest layout)
    const int linA = wave * 64 + lane;
    const int rA = linA >> 3, cA = (linA & 7) ^ (rA & 7);
    const int linB = linA + 256;
    const int rB = linB >> 3, cB = (linB & 7) ^ (rB & 7);

    // prologue: stage tile kb via global_load_lds
    {
        int s0 = kb * 64;
        gll16(QKVb + (size_t)(s0 + rA) * 6144 + 4096 + h16 * 64 + cA * 8, (char*)lK + (linA - lane) * 16);
        gll16(Vtb + (size_t)(h16 * 64 + rA) * 1024 + s0 + cA * 8,         (char*)lV + (linA - lane) * 16);
        gll16(QKVb + (size_t)(s0 + rB) * 6144 + 4096 + h16 * 64 + cB * 8, (char*)lK + (linB - lane - 256) * 16 + 4096);
        gll16(Vtb + (size_t)(h16 * 64 + rB) * 1024 + s0 + cB * 8,         (char*)lV + (linB - lane - 256) * 16 + 4096);
        gll4(ksr + h16 * 1024 + s0 + lane, (char*)lks);
        asm volatile("s_waitcnt vmcnt(0)" ::: "memory");
        __syncthreads();
    }

    for (int kt = kb; kt < ke; ++kt) {
        int s0 = kt * 64;
        const bool pf = (kt + 1 < ke);
        uint4 rk0, rv0, rk1, rv1; float rks;
        if (pf) {       // T14: issue next tile's loads now; latency hides under compute
            int s1 = s0 + 64;
            rk0 = *(const uint4*)(QKVb + (size_t)(s1 + rA) * 6144 + 4096 + h16 * 64 + cA * 8);
            rv0 = *(const uint4*)(Vtb + (size_t)(h16 * 64 + rA) * 1024 + s1 + cA * 8);
            rk1 = *(const uint4*)(QKVb + (size_t)(s1 + rB) * 6144 + 4096 + h16 * 64 + cB * 8);
            rv1 = *(const uint4*)(Vtb + (size_t)(h16 * 64 + rB) * 1024 + s1 + cB * 8);
            rks = ksr[h16 * 1024 + s1 + lane];
        }

        // QK^T swapped: A = K (rows = keys), B = Q (cols = q)
        f32x4 accs[4];
        #pragma unroll
        for (int n = 0; n < 4; ++n) accs[n] = fz;
        #pragma unroll
        for (int kk = 0; kk < 2; ++kk) {
            bf16x8 bk[4];
            #pragma unroll
            for (int n = 0; n < 4; ++n) {
                int row = n * 16 + l15;
                int ch = (kk * 4 + l4) ^ (row & 7);
                bk[n] = *(const bf16x8*)&lK[row][ch << 3];
            }
            #pragma unroll
            for (int n = 0; n < 4; ++n)
                accs[n] = __builtin_amdgcn_mfma_f32_16x16x32_bf16(bk[n], aq[kk], accs[n], 0, 0, 0);
        }

        // weights via exp2/log2
        #pragma unroll
        for (int n = 0; n < 4; ++n) {
            f32x4 ksv = *(const f32x4*)&lks[n * 16 + l4 * 4];
            float w4[4];
            #pragma unroll
            for (int r = 0; r < 4; ++r) {
                int k_abs = s0 + n * 16 + l4 * 4 + r;
                float zz = accs[n][r] * ksv[r];                       // z*log2e (ksr pre-scaled)
                float t = __builtin_amdgcn_exp2f(zz);
                float u = __builtin_amdgcn_logf(1.f + t);             // log2(1+e^z)
                u = (k_abs <= q_abs) ? u : 0.f;
                float g = __builtin_amdgcn_rcpf(1.f + __builtin_amdgcn_exp2f(-SQUISH_U * u));
                float w = LN2F * u * g;
                w = (w >= sink) ? w : 0.f;
                tot += w;
                w4[r] = w;
            }
            unsigned pa = cvt_pk_bf16(w4[0], w4[1]);
            unsigned pb = cvt_pk_bf16(w4[2], w4[3]);
            int ch = (2 * n + (l4 >> 1)) ^ (l15 & 7);
            uint2 val; val.x = pa; val.y = pb;
            *(uint2*)&lP[wave][l15][ch * 8 + (l4 & 1) * 4] = val;
        }

        // PV: A = P (rows = q), B = V^T (cols = d); per-wave private lP
        #pragma unroll
        for (int kk = 0; kk < 2; ++kk) {
            bf16x8 ap = *(const bf16x8*)&lP[wave][l15][((kk * 4 + l4) ^ (l15 & 7)) << 3];
            bf16x8 bv[4];
            #pragma unroll
            for (int n = 0; n < 4; ++n) {
                int row = n * 16 + l15;
                int ch = (kk * 4 + l4) ^ (row & 7);
                bv[n] = *(const bf16x8*)&lV[row][ch << 3];
            }
            #pragma unroll
            for (int n = 0; n < 4; ++n)
                acc_o[n] = __builtin_amdgcn_mfma_f32_16x16x32_bf16(ap, bv[n], acc_o[n], 0, 0, 0);
        }

        __syncthreads();                 // all waves done reading this tile's LDS
        if (pf) {                        // write prefetched regs -> LDS
            *(uint4*)((char*)lK + (size_t)linA * 16) = rk0;
            *(uint4*)((char*)lV + (size_t)linA * 16) = rv0;
            *(uint4*)((char*)lK + (size_t)linB * 16) = rk1;
            *(uint4*)((char*)lV + (size_t)linB * 16) = rv1;
            lks[lane] = rks;
        }
        __syncthreads();                 // next tile's data visible
    }

    tot += __shfl_xor(tot, 16, 64);
    tot += __shfl_xor(tot, 32, 64);

    if (single) {
        float tq[4];
        #pragma unroll
        for (int r = 0; r < 4; ++r) tq[r] = __shfl(tot, l4 * 4 + r, 64);
        #pragma unroll
        for (int r = 0; r < 4; ++r) {
            float inv = __builtin_amdgcn_rcpf(tq[r] + sink + 1e-6f);
            int trow = t0 + wave * 16 + l4 * 4 + r;
            #pragma unroll
            for (int n = 0; n < 4; ++n) {
                int d = n * 16 + l15;
                float val = (acc_o[n][r] + sink * lvn[d]) * inv;
                Ob[(size_t)trow * 4096 + h * 64 + d] = f2b(val);
            }
        }
    } else {
        float* Op = (kb == 0) ? Of0 : Of1;
        float* tp = (kb == 0) ? tot0 : tot1;
        if (lane < 16) tp[h * 512 + (t0 - 512) + wave * 16 + l15] = tot;
        #pragma unroll
        for (int r = 0; r < 4; ++r) {
            int pr = h * 512 + (t0 - 512) + wave * 16 + l4 * 4 + r;
            #pragma unroll
            for (int n = 0; n < 4; ++n)
                Op[(size_t)pr * 64 + n * 16 + l15] = acc_o[n][r];
        }
    }
}

// ---------- finalize split rows ----------
__global__ __launch_bounds__(256) void norm_kernel(
    const float* __restrict__ Of0, const float* __restrict__ Of1,
    const float* __restrict__ tot0, const float* __restrict__ tot1,
    const float* __restrict__ sinks, const float* __restrict__ vnulls,
    short* __restrict__ Ob) {
    int gid = blockIdx.x * 256 + threadIdx.x;
    int i4 = gid * 4;
    int row = i4 >> 6;                   // h*512 + (t-512)
    int d0 = i4 & 63;
    int h = row >> 9;
    int t = 512 + (row & 511);
    float sink = sinks[h];
    float inv = __builtin_amdgcn_rcpf(tot0[row] + tot1[row] + sink + 1e-6f);
    f32x4 a = *(const f32x4*)(Of0 + i4);
    f32x4 b = *(const f32x4*)(Of1 + i4);
    s16x4 rs;
    #pragma unroll
    for (int k = 0; k < 4; ++k)
        rs[k] = f2b((a[k] + b[k] + sink * vnulls[h * 64 + d0 + k]) * inv);
    *(s16x4*)(Ob + (size_t)t * 4096 + h * 64 + d0) = rs;
}

// ---------- launch ----------
extern "C" void kernel_launch(void* const* d_in, const int* in_sizes, int n_in,
                              void* d_out, int out_size, void* d_ws, size_t ws_size,
                              hipStream_t stream) {
    const float* X        = (const float*)d_in[0];
    const float* W_Q      = (const float*)d_in[1];
    const float* b_Q      = (const float*)d_in[2];
    const float* W_K      = (const float*)d_in[3];
    const float* b_K      = (const float*)d_in[4];
    const float* W_V      = (const float*)d_in[5];
    const float* b_V      = (const float*)d_in[6];
    const float* sinks    = (const float*)d_in[7];
    const float* v_nulls  = (const float*)d_in[8];
    const float* W_O      = (const float*)d_in[9];
    const float* W_O_bias = (const float*)d_in[10];
    float* out = (float*)d_out;
    char* ws = (char*)d_ws;

    short* Xb        = (short*)(ws + 0);          //  2 MB
    short* WbT       = (short*)(ws + 2097152);    // 12 MB
    short* WoT       = (short*)(ws + 14680064);   //  8 MB (x0.25)
    short* QKVb      = (short*)(ws + 23068672);   // 12 MB (V region unused)
    short* Vtb       = (short*)(ws + 35651584);   //  2 MB
    short* Ob        = (short*)(ws + 37748736);   //  8 MB
    float* ksr       = (float*)(ws + 46137344);   // 64 KB
    float* biasQKV   = (float*)(ws + 46202880);   // 24 KB
    float* Of0       = (float*)(ws + 50331648);   //  8.4 MB
    float* Of1       = (float*)(ws + 58720256);   //  8.4 MB
    float* tot0      = (float*)(ws + 67108864);   // 128 KB
    float* tot1      = (float*)(ws + 67239936);   // 128 KB

    prep_kernel<<<3864, 256, 0, stream>>>(X, W_Q, W_K, W_V, W_O, b_Q, b_K, b_V, W_O_bias,
                                          Xb, WbT, WoT, biasQKV, out);
    gemm_qkvf_kernel<<<dim3(48, 16), 256, 0, stream>>>(Xb, WbT, biasQKV, QKVb, Vtb, ksr,
                                                       1024, 6144, 1024);
    attn_kernel<<<dim3(64, 24), 256, 0, stream>>>(QKVb, Vtb, ksr, sinks, v_nulls, Ob,
                                                  Of0, Of1, tot0, tot1);
    norm_kernel<<<2048, 256, 0, stream>>>(Of0, Of1, tot0, tot1, sinks, v_nulls, Ob);
    gemm_op_kernel<<<dim3(8, 8, 8), 256, 0, stream>>>(Ob, WoT, out, 1024, 1024, 4096, 512);
}

// Round 10
// 195.269 us; speedup vs baseline: 1.1156x; 1.1156x over previous
//
#include <hip/hip_runtime.h>
#include <math.h>

// ---------- types ----------
typedef __attribute__((ext_vector_type(4))) float  f32x4;
typedef __attribute__((ext_vector_type(8))) short  bf16x8;   // 8 bf16 in 4 VGPRs
typedef __attribute__((ext_vector_type(4))) short  s16x4;

#define SQUISH_U 1.8137993642342178f      // pi/sqrt(3)  (applied to u = sp(z)/ln2)
#define LN2F     0.69314718055994531f

__device__ __forceinline__ float b2f(short u) {
    union { float f; unsigned b; } v; v.b = ((unsigned)(unsigned short)u) << 16; return v.f;
}
__device__ __forceinline__ short f2b(float f) {
    union { float f; unsigned b; } v; v.f = f;
    unsigned r = (v.b + 0x7FFFu + ((v.b >> 16) & 1u)) >> 16;   // RNE
    return (short)r;
}
__device__ __forceinline__ unsigned cvt_pk_bf16(float lo, float hi) {
    unsigned r;
    asm("v_cvt_pk_bf16_f32 %0, %1, %2" : "=v"(r) : "v"(lo), "v"(hi));
    return r;
}
// async global->LDS; lds base wave-uniform, HW adds lane*size
__device__ __forceinline__ void gll16(const void* g, void* l) {
    __builtin_amdgcn_global_load_lds((const __attribute__((address_space(1))) void*)g,
                                     (__attribute__((address_space(3))) void*)l, 16, 0, 0);
}
__device__ __forceinline__ void gll4(const void* g, void* l) {
    __builtin_amdgcn_global_load_lds((const __attribute__((address_space(1))) void*)g,
                                     (__attribute__((address_space(3))) void*)l, 4, 0, 0);
}

// ---------- unified prep kernel ----------
__device__ __forceinline__ void do_transpose(const float* __restrict__ src, int R, int C,
                                             short* __restrict__ dst, float scale,
                                             int c0, int r0, float (*tile)[65], int tid) {
    #pragma unroll
    for (int it = 0; it < 4; ++it) {
        int lin = it * 256 + tid;
        int r = lin >> 4, c4 = lin & 15;
        f32x4 v = *(const f32x4*)(src + (size_t)(r0 + r) * C + c0 + c4 * 4);
        #pragma unroll
        for (int k = 0; k < 4; ++k) tile[r][c4 * 4 + k] = v[k];
    }
    __syncthreads();
    #pragma unroll
    for (int it = 0; it < 4; ++it) {
        int lin = it * 256 + tid;
        int c = lin >> 4, rq = lin & 15;
        s16x4 o;
        #pragma unroll
        for (int k = 0; k < 4; ++k) o[k] = f2b(tile[rq * 4 + k][c] * scale);
        *(s16x4*)(dst + (size_t)(c0 + c) * R + r0 + rq * 4) = o;
    }
}

__global__ __launch_bounds__(256) void prep_kernel(
    const float* __restrict__ X, const float* __restrict__ W_Q, const float* __restrict__ W_K,
    const float* __restrict__ W_V, const float* __restrict__ W_O,
    const float* __restrict__ bQ, const float* __restrict__ bK, const float* __restrict__ bV,
    const float* __restrict__ bO,
    short* __restrict__ Xb, short* __restrict__ WbT, short* __restrict__ WoT,
    float* __restrict__ biasQKV, float* __restrict__ out) {
    __shared__ float tile[64][65];
    const int bid = blockIdx.x, tid = threadIdx.x;
    if (bid < 256) {
        int i = (bid * 256 + tid) * 16;
        #pragma unroll
        for (int k = 0; k < 4; ++k) {
            f32x4 v = *(const f32x4*)(X + i + k * 4);
            s16x4 o;
            o.x = f2b(v.x); o.y = f2b(v.y); o.z = f2b(v.z); o.w = f2b(v.w);
            *(s16x4*)(Xb + i + k * 4) = o;
        }
    } else if (bid < 1280) {
        int b2 = bid - 256;
        do_transpose(W_Q, 1024, 4096, WbT, 1.f, (b2 & 63) * 64, (b2 >> 6) * 64, tile, tid);
    } else if (bid < 1536) {
        int b2 = bid - 1280;
        do_transpose(W_K, 1024, 1024, WbT + 4096 * 1024, 1.f, (b2 & 15) * 64, (b2 >> 4) * 64, tile, tid);
    } else if (bid < 1792) {
        int b2 = bid - 1536;
        do_transpose(W_V, 1024, 1024, WbT + 5120 * 1024, 1.f, (b2 & 15) * 64, (b2 >> 4) * 64, tile, tid);
    } else if (bid < 2816) {
        int b2 = bid - 1792;
        do_transpose(W_O, 4096, 1024, WoT, 0.25f, (b2 & 15) * 64, (b2 >> 4) * 64, tile, tid);
    } else if (bid < 2840) {
        int i = (bid - 2816) * 256 + tid;
        if (i < 4096)      biasQKV[i] = bQ[i];
        else if (i < 5120) biasQKV[i] = bK[i - 4096];
        else               biasQKV[i] = bV[i - 5120];
    } else {
        int i = ((bid - 2840) * 256 + tid) * 4;
        f32x4 v;
        #pragma unroll
        for (int k = 0; k < 4; ++k) {
            int c = (i + k) & 1023;
            v[k] = 0.25f * (bO[c] + bO[1024 + c] + bO[2048 + c] + bO[3072 + c]);
        }
        *(f32x4*)(out + i) = v;
    }
}

// ---------- 64x128 GEMM core, dbuf counted-vmcnt (16x16x32 MFMA) ----------
#define GSTAGE_64x128(k0_, b_) do {                                            \
    _Pragma("unroll")                                                          \
    for (int it = 0; it < 2; ++it) {                                           \
        int lin0 = it * 256 + wave * 64;                                       \
        int lin = lin0 + lane;                                                 \
        int r = lin >> 3, c = (lin & 7) ^ (r & 7);                             \
        gll16(A + (size_t)(m0 + r) * K + (k0_) + c * 8, (char*)lA[b_] + lin0 * 16); \
    }                                                                          \
    _Pragma("unroll")                                                          \
    for (int it = 0; it < 4; ++it) {                                           \
        int lin0 = it * 256 + wave * 64;                                       \
        int lin = lin0 + lane;                                                 \
        int r = lin >> 3, c = (lin & 7) ^ (r & 7);                             \
        gll16(BT + (size_t)(n0 + r) * K + (k0_) + c * 8, (char*)lB[b_] + lin0 * 16); \
    } } while (0)

#define GEMM_CORE_64x128(kbeg_, kend_)                                         \
    GSTAGE_64x128(kbeg_, 0);                                                   \
    int cur = 0;                                                               \
    for (int k0 = (kbeg_); k0 < (kend_); k0 += 64) {                           \
        if (k0 + 64 < (kend_)) {                                               \
            GSTAGE_64x128(k0 + 64, cur ^ 1);                                   \
            asm volatile("s_waitcnt vmcnt(6) lgkmcnt(0)" ::: "memory");        \
        } else {                                                               \
            asm volatile("s_waitcnt vmcnt(0) lgkmcnt(0)" ::: "memory");        \
        }                                                                      \
        __builtin_amdgcn_s_barrier();                                          \
        _Pragma("unroll")                                                      \
        for (int kk = 0; kk < 2; ++kk) {                                       \
            bf16x8 af[2], bf_[4];                                              \
            _Pragma("unroll")                                                  \
            for (int m = 0; m < 2; ++m) {                                      \
                int row = wr * 32 + m * 16 + l15;                              \
                int ch = (kk * 4 + l4) ^ (row & 7);                            \
                af[m] = *(const bf16x8*)&lA[cur][row][ch << 3];                \
            }                                                                  \
            _Pragma("unroll")                                                  \
            for (int n = 0; n < 4; ++n) {                                      \
                int row = wc * 64 + n * 16 + l15;                              \
                int ch = (kk * 4 + l4) ^ (row & 7);                            \
                bf_[n] = *(const bf16x8*)&lB[cur][row][ch << 3];               \
            }                                                                  \
            _Pragma("unroll")                                                  \
            for (int m = 0; m < 2; ++m)                                        \
                _Pragma("unroll")                                              \
                for (int n = 0; n < 4; ++n)                                    \
                    acc[m][n] = __builtin_amdgcn_mfma_f32_16x16x32_bf16(af[m], bf_[n], acc[m][n], 0, 0, 0); \
        }                                                                      \
        asm volatile("" ::: "memory");                                         \
        __builtin_amdgcn_s_barrier();                                          \
        cur ^= 1;                                                              \
    }

// ---------- QKV GEMM with fused bias + RoPE + ksr + V-transpose ----------
__global__ __launch_bounds__(256, 3) void gemm_qkvf_kernel(
    const short* __restrict__ A, const short* __restrict__ BT,
    const float* __restrict__ bias, short* __restrict__ QKVb,
    short* __restrict__ Vtb, float* __restrict__ ksr,
    int M, int N, int K) {
    __shared__ short lA[2][64][64];
    __shared__ short lB[2][128][64];
    const int tid = threadIdx.x;
    const int lane = tid & 63, wave = tid >> 6;
    const int l15 = lane & 15, l4 = lane >> 4;
    const int wr = wave >> 1, wc = wave & 1;
    const int n0 = blockIdx.x * 128, m0 = blockIdx.y * 64;

    f32x4 acc[2][4];
    const f32x4 fz = {0.f, 0.f, 0.f, 0.f};
    #pragma unroll
    for (int m = 0; m < 2; ++m)
        #pragma unroll
        for (int n = 0; n < 4; ++n) acc[m][n] = fz;

    GEMM_CORE_64x128(0, K);

    const int head = blockIdx.x * 2 + wc;
    float bn[4];
    #pragma unroll
    for (int n = 0; n < 4; ++n) bn[n] = bias[head * 64 + n * 16 + l15];
    #pragma unroll
    for (int m = 0; m < 2; ++m)
        #pragma unroll
        for (int n = 0; n < 4; ++n)
            #pragma unroll
            for (int r = 0; r < 4; ++r) acc[m][n][r] += bn[n];

    if (head < 80) {
        // RoPE applied on fp32 acc
        const float invf0 = __builtin_exp2f(-(float)l15 * 0.41524101186092033f); // 10000^(-l15/32)
        const float invf1 = invf0 * 0.01f;
        const int p1 = (2 * l15) & 15, p2 = (2 * l15 + 1) & 15;
        #pragma unroll
        for (int m = 0; m < 2; ++m) {
            int tb = m0 + wr * 32 + m * 16 + l4 * 4;
            float x1lo[4], x2lo[4], x1hi[4], x2hi[4];
            #pragma unroll
            for (int r = 0; r < 4; ++r) {
                float a0 = __shfl(acc[m][0][r], p1, 16), b0 = __shfl(acc[m][1][r], p1, 16);
                float a1 = __shfl(acc[m][0][r], p2, 16), b1 = __shfl(acc[m][1][r], p2, 16);
                x1lo[r] = (l15 < 8) ? a0 : b0;
                x2lo[r] = (l15 < 8) ? a1 : b1;
                float c0 = __shfl(acc[m][2][r], p1, 16), d0 = __shfl(acc[m][3][r], p1, 16);
                float c1 = __shfl(acc[m][2][r], p2, 16), d1 = __shfl(acc[m][3][r], p2, 16);
                x1hi[r] = (l15 < 8) ? c0 : d0;
                x2hi[r] = (l15 < 8) ? c1 : d1;
            }
            #pragma unroll
            for (int r = 0; r < 4; ++r) {
                float tf = (float)(tb + r);
                float f0 = tf * invf0, f1 = tf * invf1;
                float s0 = __sinf(f0), c0 = __cosf(f0);
                float s1 = __sinf(f1), c1 = __cosf(f1);
                acc[m][0][r] = x1lo[r] * c0 - x2lo[r] * s0;
                acc[m][2][r] = x1lo[r] * s0 + x2lo[r] * c0;
                acc[m][1][r] = x1hi[r] * c1 - x2hi[r] * s1;
                acc[m][3][r] = x1hi[r] * s1 + x2hi[r] * c1;
            }
        }
    }

    if (head >= 80) {
        const int h16 = head - 80;
        #pragma unroll
        for (int m = 0; m < 2; ++m) {
            int tb = m0 + wr * 32 + m * 16 + l4 * 4;
            #pragma unroll
            for (int n = 0; n < 4; ++n) {
                s16x4 o;
                #pragma unroll
                for (int r = 0; r < 4; ++r) o[r] = f2b(acc[m][n][r]);
                *(s16x4*)(Vtb + (size_t)(h16 * 64 + n * 16 + l15) * 1024 + tb) = o;
            }
        }
    } else {
        const size_t coff = (head < 64) ? (size_t)head * 64 : (size_t)(4096 + (head - 64) * 64);
        #pragma unroll
        for (int m = 0; m < 2; ++m)
            #pragma unroll
            for (int r = 0; r < 4; ++r) {
                int row = m0 + wr * 32 + m * 16 + l4 * 4 + r;
                #pragma unroll
                for (int n = 0; n < 4; ++n)
                    QKVb[(size_t)row * 6144 + coff + n * 16 + l15] = f2b(acc[m][n][r]);
            }
        if (head >= 64) {
            const int h16 = head - 64;
            #pragma unroll
            for (int m = 0; m < 2; ++m)
                #pragma unroll
                for (int r = 0; r < 4; ++r) {
                    float ss = 0.f;
                    #pragma unroll
                    for (int n = 0; n < 4; ++n) ss += acc[m][n][r] * acc[m][n][r];
                    ss += __shfl_xor(ss, 1, 16);
                    ss += __shfl_xor(ss, 2, 16);
                    ss += __shfl_xor(ss, 4, 16);
                    ss += __shfl_xor(ss, 8, 16);
                    if (l15 == 0)
                        ksr[h16 * 1024 + m0 + wr * 32 + m * 16 + l4 * 4 + r] =
                            0.18033688011112042f * rsqrtf(fmaxf(ss, 1e-6f));   // log2e * 0.125 * rsqrt
                }
        }
    }
}

// ---------- out-proj: 64x128 tile, split-K=4, fp32 atomic accumulate (R6-proven) ----------
__global__ __launch_bounds__(256, 3) void gemm_op_kernel(
    const short* __restrict__ A, const short* __restrict__ BT,
    float* __restrict__ out, int M, int N, int K, int KSLICE) {
    __shared__ short lA[2][64][64];
    __shared__ short lB[2][128][64];
    const int tid = threadIdx.x;
    const int lane = tid & 63, wave = tid >> 6;
    const int l15 = lane & 15, l4 = lane >> 4;
    const int wr = wave >> 1, wc = wave & 1;
    const int n0 = blockIdx.x * 128, m0 = blockIdx.y * 64;
    const int kbeg = blockIdx.z * KSLICE, kend = kbeg + KSLICE;

    f32x4 acc[2][4];
    const f32x4 fz = {0.f, 0.f, 0.f, 0.f};
    #pragma unroll
    for (int m = 0; m < 2; ++m)
        #pragma unroll
        for (int n = 0; n < 4; ++n) acc[m][n] = fz;

    GEMM_CORE_64x128(kbeg, kend);

    #pragma unroll
    for (int m = 0; m < 2; ++m)
        #pragma unroll
        for (int n = 0; n < 4; ++n)
            #pragma unroll
            for (int r = 0; r < 4; ++r) {
                int row = m0 + wr * 32 + m * 16 + l4 * 4 + r;
                int col = n0 + wc * 64 + n * 16 + l15;
                unsafeAtomicAdd(&out[(size_t)row * N + col], acc[m][n][r]);
            }
}

// ---------- attention: k-split + 2-branch K/V sharing ----------
// Heads h and h+32 share h16 (same K/V/ksr). grid (32 pairs, 24 slots).
// Per tile: stage K/V once, compute both heads -> staging and barriers halved per unit work.
__constant__ __device__ const signed char TQT[24] = {15,15,14, 7,14,13,13,12, 6,12,11,11,10, 5,10, 9, 9, 8, 4, 8, 3, 2, 1, 0};
__constant__ __device__ const signed char TKB[24] = { 0, 8, 0, 0, 8, 0, 7, 0, 0, 7, 0, 6, 0, 0, 6, 0, 5, 0, 0, 5, 0, 0, 0, 0};
__constant__ __device__ const signed char TKE[24] = { 8,16, 8, 8,15, 7,14, 7, 7,13, 6,12, 6, 6,11, 5,10, 5, 5, 9, 4, 3, 2, 1};

__global__ __launch_bounds__(256, 4) void attn_kernel(
    const short* __restrict__ QKVb, const short* __restrict__ Vtb,
    const float* __restrict__ ksr, const float* __restrict__ sinks,
    const float* __restrict__ vnulls, short* __restrict__ Ob,
    float* __restrict__ Of0, float* __restrict__ Of1,
    float* __restrict__ tot0, float* __restrict__ tot1) {
    __shared__ short lK[64][64];
    __shared__ short lV[64][64];
    __shared__ float lks[64];
    __shared__ float lvn[2][64];
    __shared__ short lP[4][16][64];

    const int tid = threadIdx.x;
    const int lane = tid & 63, wave = tid >> 6;
    const int l15 = lane & 15, l4 = lane >> 4;
    const int pid = blockIdx.x;              // 0..31: heads {pid, pid+32}
    const int slot = blockIdx.y;
    const int qt = TQT[slot], kb = TKB[slot], ke = TKE[slot];
    const bool single = (kb == 0) && (ke == qt + 1);
    const int h16 = pid & 15;
    const int t0 = qt * 64;
    const int hh0 = pid, hh1 = pid + 32;
    const float sk0 = sinks[hh0], sk1 = sinks[hh1];
    if (tid < 64)       lvn[0][tid] = vnulls[hh0 * 64 + tid];
    else if (tid < 128) lvn[1][tid - 64] = vnulls[hh1 * 64 + (tid - 64)];

    const int q_abs = t0 + wave * 16 + l15;
    bf16x8 aq[2][2];
    #pragma unroll
    for (int kk = 0; kk < 2; ++kk) {
        aq[0][kk] = *(const bf16x8*)(QKVb + (size_t)q_abs * 6144 + hh0 * 64 + kk * 32 + l4 * 8);
        aq[1][kk] = *(const bf16x8*)(QKVb + (size_t)q_abs * 6144 + hh1 * 64 + kk * 32 + l4 * 8);
    }

    const f32x4 fz = {0.f, 0.f, 0.f, 0.f};
    f32x4 acc_o[2][4];
    float tot[2] = {0.f, 0.f};
    #pragma unroll
    for (int b = 0; b < 2; ++b)
        #pragma unroll
        for (int n = 0; n < 4; ++n) acc_o[b][n] = fz;

#define ASTAGE(s0_) do {                                                              \
    int lin0 = wave * 64;                                                             \
    int lin = lin0 + lane;                                                            \
    int r = lin >> 3, c = (lin & 7) ^ (r & 7);                                        \
    gll16(QKVb + (size_t)((s0_) + r) * 6144 + 4096 + h16 * 64 + c * 8, (char*)lK + lin0 * 16); \
    gll16(Vtb + (size_t)(h16 * 64 + r) * 1024 + (s0_) + c * 8,         (char*)lV + lin0 * 16); \
    lin0 += 256; lin = lin0 + lane; r = lin >> 3; c = (lin & 7) ^ (r & 7);            \
    gll16(QKVb + (size_t)((s0_) + r) * 6144 + 4096 + h16 * 64 + c * 8, (char*)lK + lin0 * 16); \
    gll16(Vtb + (size_t)(h16 * 64 + r) * 1024 + (s0_) + c * 8,         (char*)lV + lin0 * 16); \
    gll4(ksr + h16 * 1024 + (s0_) + lane, (char*)lks);                                \
} while (0)

    for (int kt = kb; kt < ke; ++kt) {
        int s0 = kt * 64;
        __syncthreads();                         // previous tile's LDS reads complete
        ASTAGE(s0);
        asm volatile("s_waitcnt vmcnt(0)" ::: "memory");
        __syncthreads();

        #pragma unroll
        for (int b = 0; b < 2; ++b) {
            const float sink = b ? sk1 : sk0;
            // QK^T swapped: A = K (rows = keys), B = Q (cols = q)
            f32x4 accs[4];
            #pragma unroll
            for (int n = 0; n < 4; ++n) accs[n] = fz;
            #pragma unroll
            for (int kk = 0; kk < 2; ++kk) {
                bf16x8 bk[4];
                #pragma unroll
                for (int n = 0; n < 4; ++n) {
                    int row = n * 16 + l15;
                    int ch = (kk * 4 + l4) ^ (row & 7);
                    bk[n] = *(const bf16x8*)&lK[row][ch << 3];
                }
                #pragma unroll
                for (int n = 0; n < 4; ++n)
                    accs[n] = __builtin_amdgcn_mfma_f32_16x16x32_bf16(bk[n], aq[b][kk], accs[n], 0, 0, 0);
            }

            // weights via exp2/log2:  u = log2(1+2^(z*log2e));  w = ln2*u*sigmoid-gate
            #pragma unroll
            for (int n = 0; n < 4; ++n) {
                f32x4 ksv = *(const f32x4*)&lks[n * 16 + l4 * 4];
                float w4[4];
                #pragma unroll
                for (int r = 0; r < 4; ++r) {
                    int k_abs = s0 + n * 16 + l4 * 4 + r;
                    float zz = accs[n][r] * ksv[r];                       // z*log2e (ksr pre-scaled)
                    float t = __builtin_amdgcn_exp2f(zz);
                    float u = __builtin_amdgcn_logf(1.f + t);             // log2(1+e^z)
                    u = (k_abs <= q_abs) ? u : 0.f;
                    float g = __builtin_amdgcn_rcpf(1.f + __builtin_amdgcn_exp2f(-SQUISH_U * u));
                    float w = LN2F * u * g;
                    w = (w >= sink) ? w : 0.f;
                    tot[b] += w;
                    w4[r] = w;
                }
                unsigned pa = cvt_pk_bf16(w4[0], w4[1]);
                unsigned pb = cvt_pk_bf16(w4[2], w4[3]);
                int ch = (2 * n + (l4 >> 1)) ^ (l15 & 7);
                uint2 val; val.x = pa; val.y = pb;
                *(uint2*)&lP[wave][l15][ch * 8 + (l4 & 1) * 4] = val;
            }

            // PV: A = P (rows = q), B = V^T (cols = d); per-wave private lP (in-order LDS)
            #pragma unroll
            for (int kk = 0; kk < 2; ++kk) {
                bf16x8 ap = *(const bf16x8*)&lP[wave][l15][((kk * 4 + l4) ^ (l15 & 7)) << 3];
                bf16x8 bv[4];
                #pragma unroll
                for (int n = 0; n < 4; ++n) {
                    int row = n * 16 + l15;
                    int ch = (kk * 4 + l4) ^ (row & 7);
                    bv[n] = *(const bf16x8*)&lV[row][ch << 3];
                }
                #pragma unroll
                for (int n = 0; n < 4; ++n)
                    acc_o[b][n] = __builtin_amdgcn_mfma_f32_16x16x32_bf16(ap, bv[n], acc_o[b][n], 0, 0, 0);
            }
        }
    }
#undef ASTAGE

    #pragma unroll
    for (int b = 0; b < 2; ++b) {
        const int hh = b ? hh1 : hh0;
        const float sink = b ? sk1 : sk0;
        float t = tot[b];
        t += __shfl_xor(t, 16, 64);
        t += __shfl_xor(t, 32, 64);

        if (single) {
            float tq[4];
            #pragma unroll
            for (int r = 0; r < 4; ++r) tq[r] = __shfl(t, l4 * 4 + r, 64);
            #pragma unroll
            for (int r = 0; r < 4; ++r) {
                float inv = __builtin_amdgcn_rcpf(tq[r] + sink + 1e-6f);
                int trow = t0 + wave * 16 + l4 * 4 + r;
                #pragma unroll
                for (int n = 0; n < 4; ++n) {
                    int d = n * 16 + l15;
                    float val = (acc_o[b][n][r] + sink * lvn[b][d]) * inv;
                    Ob[(size_t)trow * 4096 + hh * 64 + d] = f2b(val);
                }
            }
        } else {
            // split rows (qt>=8): two blocks per row, each writes its own partial buffer
            float* Op = (kb == 0) ? Of0 : Of1;
            float* tp = (kb == 0) ? tot0 : tot1;
            if (lane < 16) tp[hh * 512 + (t0 - 512) + wave * 16 + l15] = t;
            #pragma unroll
            for (int r = 0; r < 4; ++r) {
                int pr = hh * 512 + (t0 - 512) + wave * 16 + l4 * 4 + r;
                #pragma unroll
                for (int n = 0; n < 4; ++n)
                    Op[(size_t)pr * 64 + n * 16 + l15] = acc_o[b][n][r];
            }
        }
    }
}

// ---------- finalize split rows ----------
__global__ __launch_bounds__(256) void norm_kernel(
    const float* __restrict__ Of0, const float* __restrict__ Of1,
    const float* __restrict__ tot0, const float* __restrict__ tot1,
    const float* __restrict__ sinks, const float* __restrict__ vnulls,
    short* __restrict__ Ob) {
    int gid = blockIdx.x * 256 + threadIdx.x;
    int i4 = gid * 4;
    int row = i4 >> 6;                   // h*512 + (t-512)
    int d0 = i4 & 63;
    int h = row >> 9;
    int t = 512 + (row & 511);
    float sink = sinks[h];
    float inv = __builtin_amdgcn_rcpf(tot0[row] + tot1[row] + sink + 1e-6f);
    f32x4 a = *(const f32x4*)(Of0 + i4);
    f32x4 b = *(const f32x4*)(Of1 + i4);
    s16x4 rs;
    #pragma unroll
    for (int k = 0; k < 4; ++k)
        rs[k] = f2b((a[k] + b[k] + sink * vnulls[h * 64 + d0 + k]) * inv);
    *(s16x4*)(Ob + (size_t)t * 4096 + h * 64 + d0) = rs;
}

// ---------- launch ----------
extern "C" void kernel_launch(void* const* d_in, const int* in_sizes, int n_in,
                              void* d_out, int out_size, void* d_ws, size_t ws_size,
                              hipStream_t stream) {
    const float* X        = (const float*)d_in[0];
    const float* W_Q      = (const float*)d_in[1];
    const float* b_Q      = (const float*)d_in[2];
    const float* W_K      = (const float*)d_in[3];
    const float* b_K      = (const float*)d_in[4];
    const float* W_V      = (const float*)d_in[5];
    const float* b_V      = (const float*)d_in[6];
    const float* sinks    = (const float*)d_in[7];
    const float* v_nulls  = (const float*)d_in[8];
    const float* W_O      = (const float*)d_in[9];
    const float* W_O_bias = (const float*)d_in[10];
    float* out = (float*)d_out;
    char* ws = (char*)d_ws;

    short* Xb        = (short*)(ws + 0);          //  2 MB
    short* WbT       = (short*)(ws + 2097152);    // 12 MB
    short* WoT       = (short*)(ws + 14680064);   //  8 MB (x0.25)
    short* QKVb      = (short*)(ws + 23068672);   // 12 MB (V region unused)
    short* Vtb       = (short*)(ws + 35651584);   //  2 MB
    short* Ob        = (short*)(ws + 37748736);   //  8 MB
    float* ksr       = (float*)(ws + 46137344);   // 64 KB
    float* biasQKV   = (float*)(ws + 46202880);   // 24 KB
    float* Of0       = (float*)(ws + 50331648);   //  8.4 MB
    float* Of1       = (float*)(ws + 58720256);   //  8.4 MB
    float* tot0      = (float*)(ws + 67108864);   // 128 KB
    float* tot1      = (float*)(ws + 67239936);   // 128 KB

    prep_kernel<<<3864, 256, 0, stream>>>(X, W_Q, W_K, W_V, W_O, b_Q, b_K, b_V, W_O_bias,
                                          Xb, WbT, WoT, biasQKV, out);
    gemm_qkvf_kernel<<<dim3(48, 16), 256, 0, stream>>>(Xb, WbT, biasQKV, QKVb, Vtb, ksr,
                                                       1024, 6144, 1024);
    attn_kernel<<<dim3(32, 24), 256, 0, stream>>>(QKVb, Vtb, ksr, sinks, v_nulls, Ob,
                                                  Of0, Of1, tot0, tot1);
    norm_kernel<<<2048, 256, 0, stream>>>(Of0, Of1, tot0, tot1, sinks, v_nulls, Ob);
    gemm_op_kernel<<<dim3(8, 16, 4), 256, 0, stream>>>(Ob, WoT, out, 1024, 1024, 4096, 1024);
}

// Round 11
// 183.921 us; speedup vs baseline: 1.1844x; 1.0617x over previous
//
#include <hip/hip_runtime.h>
#include <math.h>

// ---------- types ----------
typedef __attribute__((ext_vector_type(4))) float  f32x4;
typedef __attribute__((ext_vector_type(8))) short  bf16x8;   // 8 bf16 in 4 VGPRs
typedef __attribute__((ext_vector_type(4))) short  s16x4;

#define SQUISH_U 1.8137993642342178f      // pi/sqrt(3)  (gate operates on u = sp(z)/ln2)
#define LOG2E    1.4426950408889634f

__device__ __forceinline__ float b2f(short u) {
    union { float f; unsigned b; } v; v.b = ((unsigned)(unsigned short)u) << 16; return v.f;
}
__device__ __forceinline__ short f2b(float f) {
    union { float f; unsigned b; } v; v.f = f;
    unsigned r = (v.b + 0x7FFFu + ((v.b >> 16) & 1u)) >> 16;   // RNE
    return (short)r;
}
__device__ __forceinline__ unsigned cvt_pk_bf16(float lo, float hi) {
    unsigned r;
    asm("v_cvt_pk_bf16_f32 %0, %1, %2" : "=v"(r) : "v"(lo), "v"(hi));
    return r;
}
// async global->LDS; lds base wave-uniform, HW adds lane*size
__device__ __forceinline__ void gll16(const void* g, void* l) {
    __builtin_amdgcn_global_load_lds((const __attribute__((address_space(1))) void*)g,
                                     (__attribute__((address_space(3))) void*)l, 16, 0, 0);
}
__device__ __forceinline__ void gll4(const void* g, void* l) {
    __builtin_amdgcn_global_load_lds((const __attribute__((address_space(1))) void*)g,
                                     (__attribute__((address_space(3))) void*)l, 4, 0, 0);
}

// ---------- unified prep kernel ----------
__device__ __forceinline__ void do_transpose(const float* __restrict__ src, int R, int C,
                                             short* __restrict__ dst, float scale,
                                             int c0, int r0, float (*tile)[65], int tid) {
    #pragma unroll
    for (int it = 0; it < 4; ++it) {
        int lin = it * 256 + tid;
        int r = lin >> 4, c4 = lin & 15;
        f32x4 v = *(const f32x4*)(src + (size_t)(r0 + r) * C + c0 + c4 * 4);
        #pragma unroll
        for (int k = 0; k < 4; ++k) tile[r][c4 * 4 + k] = v[k];
    }
    __syncthreads();
    #pragma unroll
    for (int it = 0; it < 4; ++it) {
        int lin = it * 256 + tid;
        int c = lin >> 4, rq = lin & 15;
        s16x4 o;
        #pragma unroll
        for (int k = 0; k < 4; ++k) o[k] = f2b(tile[rq * 4 + k][c] * scale);
        *(s16x4*)(dst + (size_t)(c0 + c) * R + r0 + rq * 4) = o;
    }
}

__global__ __launch_bounds__(256) void prep_kernel(
    const float* __restrict__ X, const float* __restrict__ W_Q, const float* __restrict__ W_K,
    const float* __restrict__ W_V, const float* __restrict__ W_O,
    const float* __restrict__ bQ, const float* __restrict__ bK, const float* __restrict__ bV,
    const float* __restrict__ bO,
    short* __restrict__ Xb, short* __restrict__ WbT, short* __restrict__ WoT,
    float* __restrict__ biasQKV, float* __restrict__ out) {
    __shared__ float tile[64][65];
    const int bid = blockIdx.x, tid = threadIdx.x;
    if (bid < 256) {
        int i = (bid * 256 + tid) * 16;
        #pragma unroll
        for (int k = 0; k < 4; ++k) {
            f32x4 v = *(const f32x4*)(X + i + k * 4);
            s16x4 o;
            o.x = f2b(v.x); o.y = f2b(v.y); o.z = f2b(v.z); o.w = f2b(v.w);
            *(s16x4*)(Xb + i + k * 4) = o;
        }
    } else if (bid < 1280) {
        int b2 = bid - 256;
        do_transpose(W_Q, 1024, 4096, WbT, 1.f, (b2 & 63) * 64, (b2 >> 6) * 64, tile, tid);
    } else if (bid < 1536) {
        int b2 = bid - 1280;
        do_transpose(W_K, 1024, 1024, WbT + 4096 * 1024, 1.f, (b2 & 15) * 64, (b2 >> 4) * 64, tile, tid);
    } else if (bid < 1792) {
        int b2 = bid - 1536;
        do_transpose(W_V, 1024, 1024, WbT + 5120 * 1024, 1.f, (b2 & 15) * 64, (b2 >> 4) * 64, tile, tid);
    } else if (bid < 2816) {
        int b2 = bid - 1792;
        do_transpose(W_O, 4096, 1024, WoT, 0.25f, (b2 & 15) * 64, (b2 >> 4) * 64, tile, tid);
    } else if (bid < 2840) {
        int i = (bid - 2816) * 256 + tid;
        if (i < 4096)      biasQKV[i] = bQ[i];
        else if (i < 5120) biasQKV[i] = bK[i - 4096];
        else               biasQKV[i] = bV[i - 5120];
    } else {
        int i = ((bid - 2840) * 256 + tid) * 4;
        f32x4 v;
        #pragma unroll
        for (int k = 0; k < 4; ++k) {
            int c = (i + k) & 1023;
            v[k] = 0.25f * (bO[c] + bO[1024 + c] + bO[2048 + c] + bO[3072 + c]);
        }
        *(f32x4*)(out + i) = v;
    }
}

// ---------- 64x128 GEMM core, dbuf counted-vmcnt (16x16x32 MFMA) ----------
#define GSTAGE_64x128(k0_, b_) do {                                            \
    _Pragma("unroll")                                                          \
    for (int it = 0; it < 2; ++it) {                                           \
        int lin0 = it * 256 + wave * 64;                                       \
        int lin = lin0 + lane;                                                 \
        int r = lin >> 3, c = (lin & 7) ^ (r & 7);                             \
        gll16(A + (size_t)(m0 + r) * K + (k0_) + c * 8, (char*)lA[b_] + lin0 * 16); \
    }                                                                          \
    _Pragma("unroll")                                                          \
    for (int it = 0; it < 4; ++it) {                                           \
        int lin0 = it * 256 + wave * 64;                                       \
        int lin = lin0 + lane;                                                 \
        int r = lin >> 3, c = (lin & 7) ^ (r & 7);                             \
        gll16(BT + (size_t)(n0 + r) * K + (k0_) + c * 8, (char*)lB[b_] + lin0 * 16); \
    } } while (0)

#define GEMM_CORE_64x128(kbeg_, kend_)                                         \
    GSTAGE_64x128(kbeg_, 0);                                                   \
    int cur = 0;                                                               \
    for (int k0 = (kbeg_); k0 < (kend_); k0 += 64) {                           \
        if (k0 + 64 < (kend_)) {                                               \
            GSTAGE_64x128(k0 + 64, cur ^ 1);                                   \
            asm volatile("s_waitcnt vmcnt(6) lgkmcnt(0)" ::: "memory");        \
        } else {                                                               \
            asm volatile("s_waitcnt vmcnt(0) lgkmcnt(0)" ::: "memory");        \
        }                                                                      \
        __builtin_amdgcn_s_barrier();                                          \
        _Pragma("unroll")                                                      \
        for (int kk = 0; kk < 2; ++kk) {                                       \
            bf16x8 af[2], bf_[4];                                              \
            _Pragma("unroll")                                                  \
            for (int m = 0; m < 2; ++m) {                                      \
                int row = wr * 32 + m * 16 + l15;                              \
                int ch = (kk * 4 + l4) ^ (row & 7);                            \
                af[m] = *(const bf16x8*)&lA[cur][row][ch << 3];                \
            }                                                                  \
            _Pragma("unroll")                                                  \
            for (int n = 0; n < 4; ++n) {                                      \
                int row = wc * 64 + n * 16 + l15;                              \
                int ch = (kk * 4 + l4) ^ (row & 7);                            \
                bf_[n] = *(const bf16x8*)&lB[cur][row][ch << 3];               \
            }                                                                  \
            _Pragma("unroll")                                                  \
            for (int m = 0; m < 2; ++m)                                        \
                _Pragma("unroll")                                              \
                for (int n = 0; n < 4; ++n)                                    \
                    acc[m][n] = __builtin_amdgcn_mfma_f32_16x16x32_bf16(af[m], bf_[n], acc[m][n], 0, 0, 0); \
        }                                                                      \
        asm volatile("" ::: "memory");                                         \
        __builtin_amdgcn_s_barrier();                                          \
        cur ^= 1;                                                              \
    }

// ---------- QKV GEMM with fused bias + RoPE + ksr + V-transpose ----------
__global__ __launch_bounds__(256, 3) void gemm_qkvf_kernel(
    const short* __restrict__ A, const short* __restrict__ BT,
    const float* __restrict__ bias, short* __restrict__ QKVb,
    short* __restrict__ Vtb, float* __restrict__ ksr,
    int M, int N, int K) {
    __shared__ short lA[2][64][64];
    __shared__ short lB[2][128][64];
    const int tid = threadIdx.x;
    const int lane = tid & 63, wave = tid >> 6;
    const int l15 = lane & 15, l4 = lane >> 4;
    const int wr = wave >> 1, wc = wave & 1;
    const int n0 = blockIdx.x * 128, m0 = blockIdx.y * 64;

    f32x4 acc[2][4];
    const f32x4 fz = {0.f, 0.f, 0.f, 0.f};
    #pragma unroll
    for (int m = 0; m < 2; ++m)
        #pragma unroll
        for (int n = 0; n < 4; ++n) acc[m][n] = fz;

    GEMM_CORE_64x128(0, K);

    const int head = blockIdx.x * 2 + wc;
    float bn[4];
    #pragma unroll
    for (int n = 0; n < 4; ++n) bn[n] = bias[head * 64 + n * 16 + l15];
    #pragma unroll
    for (int m = 0; m < 2; ++m)
        #pragma unroll
        for (int n = 0; n < 4; ++n)
            #pragma unroll
            for (int r = 0; r < 4; ++r) acc[m][n][r] += bn[n];

    if (head < 80) {
        // RoPE applied on fp32 acc
        const float invf0 = __builtin_exp2f(-(float)l15 * 0.41524101186092033f); // 10000^(-l15/32)
        const float invf1 = invf0 * 0.01f;
        const int p1 = (2 * l15) & 15, p2 = (2 * l15 + 1) & 15;
        #pragma unroll
        for (int m = 0; m < 2; ++m) {
            int tb = m0 + wr * 32 + m * 16 + l4 * 4;
            float x1lo[4], x2lo[4], x1hi[4], x2hi[4];
            #pragma unroll
            for (int r = 0; r < 4; ++r) {
                float a0 = __shfl(acc[m][0][r], p1, 16), b0 = __shfl(acc[m][1][r], p1, 16);
                float a1 = __shfl(acc[m][0][r], p2, 16), b1 = __shfl(acc[m][1][r], p2, 16);
                x1lo[r] = (l15 < 8) ? a0 : b0;
                x2lo[r] = (l15 < 8) ? a1 : b1;
                float c0 = __shfl(acc[m][2][r], p1, 16), d0 = __shfl(acc[m][3][r], p1, 16);
                float c1 = __shfl(acc[m][2][r], p2, 16), d1 = __shfl(acc[m][3][r], p2, 16);
                x1hi[r] = (l15 < 8) ? c0 : d0;
                x2hi[r] = (l15 < 8) ? c1 : d1;
            }
            #pragma unroll
            for (int r = 0; r < 4; ++r) {
                float tf = (float)(tb + r);
                float f0 = tf * invf0, f1 = tf * invf1;
                float s0 = __sinf(f0), c0 = __cosf(f0);
                float s1 = __sinf(f1), c1 = __cosf(f1);
                acc[m][0][r] = x1lo[r] * c0 - x2lo[r] * s0;
                acc[m][2][r] = x1lo[r] * s0 + x2lo[r] * c0;
                acc[m][1][r] = x1hi[r] * c1 - x2hi[r] * s1;
                acc[m][3][r] = x1hi[r] * s1 + x2hi[r] * c1;
            }
        }
    }

    if (head >= 80) {
        const int h16 = head - 80;
        #pragma unroll
        for (int m = 0; m < 2; ++m) {
            int tb = m0 + wr * 32 + m * 16 + l4 * 4;
            #pragma unroll
            for (int n = 0; n < 4; ++n) {
                s16x4 o;
                #pragma unroll
                for (int r = 0; r < 4; ++r) o[r] = f2b(acc[m][n][r]);
                *(s16x4*)(Vtb + (size_t)(h16 * 64 + n * 16 + l15) * 1024 + tb) = o;
            }
        }
    } else {
        const size_t coff = (head < 64) ? (size_t)head * 64 : (size_t)(4096 + (head - 64) * 64);
        #pragma unroll
        for (int m = 0; m < 2; ++m)
            #pragma unroll
            for (int r = 0; r < 4; ++r) {
                int row = m0 + wr * 32 + m * 16 + l4 * 4 + r;
                #pragma unroll
                for (int n = 0; n < 4; ++n)
                    QKVb[(size_t)row * 6144 + coff + n * 16 + l15] = f2b(acc[m][n][r]);
            }
        if (head >= 64) {
            const int h16 = head - 64;
            #pragma unroll
            for (int m = 0; m < 2; ++m)
                #pragma unroll
                for (int r = 0; r < 4; ++r) {
                    float ss = 0.f;
                    #pragma unroll
                    for (int n = 0; n < 4; ++n) ss += acc[m][n][r] * acc[m][n][r];
                    ss += __shfl_xor(ss, 1, 16);
                    ss += __shfl_xor(ss, 2, 16);
                    ss += __shfl_xor(ss, 4, 16);
                    ss += __shfl_xor(ss, 8, 16);
                    if (l15 == 0)
                        ksr[h16 * 1024 + m0 + wr * 32 + m * 16 + l4 * 4 + r] =
                            0.18033688011112042f * rsqrtf(fmaxf(ss, 1e-6f));   // log2e * 0.125 * rsqrt
                }
        }
    }
}

// ---------- out-proj: 64x128 tile, split-K=4, fp32 atomic accumulate (R6-proven) ----------
__global__ __launch_bounds__(256, 3) void gemm_op_kernel(
    const short* __restrict__ A, const short* __restrict__ BT,
    float* __restrict__ out, int M, int N, int K, int KSLICE) {
    __shared__ short lA[2][64][64];
    __shared__ short lB[2][128][64];
    const int tid = threadIdx.x;
    const int lane = tid & 63, wave = tid >> 6;
    const int l15 = lane & 15, l4 = lane >> 4;
    const int wr = wave >> 1, wc = wave & 1;
    const int n0 = blockIdx.x * 128, m0 = blockIdx.y * 64;
    const int kbeg = blockIdx.z * KSLICE, kend = kbeg + KSLICE;

    f32x4 acc[2][4];
    const f32x4 fz = {0.f, 0.f, 0.f, 0.f};
    #pragma unroll
    for (int m = 0; m < 2; ++m)
        #pragma unroll
        for (int n = 0; n < 4; ++n) acc[m][n] = fz;

    GEMM_CORE_64x128(kbeg, kend);

    #pragma unroll
    for (int m = 0; m < 2; ++m)
        #pragma unroll
        for (int n = 0; n < 4; ++n)
            #pragma unroll
            for (int r = 0; r < 4; ++r) {
                int row = m0 + wr * 32 + m * 16 + l4 * 4 + r;
                int col = n0 + wc * 64 + n * 16 + l15;
                unsafeAtomicAdd(&out[(size_t)row * N + col], acc[m][n][r]);
            }
}

// ---------- attention (R6 structure + VALU-trimmed softmax) ----------
// P stores w' = w/ln2; divisor and sink terms rescaled by log2e (exact algebra).
__constant__ __device__ const signed char TQT[24] = {15,15,14, 7,14,13,13,12, 6,12,11,11,10, 5,10, 9, 9, 8, 4, 8, 3, 2, 1, 0};
__constant__ __device__ const signed char TKB[24] = { 0, 8, 0, 0, 8, 0, 7, 0, 0, 7, 0, 6, 0, 0, 6, 0, 5, 0, 0, 5, 0, 0, 0, 0};
__constant__ __device__ const signed char TKE[24] = { 8,16, 8, 8,15, 7,14, 7, 7,13, 6,12, 6, 6,11, 5,10, 5, 5, 9, 4, 3, 2, 1};

__global__ __launch_bounds__(256, 6) void attn_kernel(
    const short* __restrict__ QKVb, const short* __restrict__ Vtb,
    const float* __restrict__ ksr, const float* __restrict__ sinks,
    const float* __restrict__ vnulls, short* __restrict__ Ob,
    float* __restrict__ Of0, float* __restrict__ Of1,
    float* __restrict__ tot0, float* __restrict__ tot1) {
    __shared__ short lK[64][64];
    __shared__ short lV[64][64];
    __shared__ float lks[64];
    __shared__ float lvn[64];
    __shared__ short lP[4][16][64];

    const int tid = threadIdx.x;
    const int lane = tid & 63, wave = tid >> 6;
    const int l15 = lane & 15, l4 = lane >> 4;
    const int h = blockIdx.x;
    const int slot = blockIdx.y;
    const int qt = TQT[slot], kb = TKB[slot], ke = TKE[slot];
    const bool single = (kb == 0) && (ke == qt + 1);
    const int h16 = h & 15;
    const int t0 = qt * 64;
    const float sinkp = sinks[h] * LOG2E;          // threshold & vnull scale (w'-domain)
    if (tid < 64) lvn[tid] = vnulls[h * 64 + tid];

    const int qrel = wave * 16 + l15;
    const int q_abs = t0 + qrel;
    bf16x8 aq[2];
    #pragma unroll
    for (int kk = 0; kk < 2; ++kk)
        aq[kk] = *(const bf16x8*)(QKVb + (size_t)q_abs * 6144 + h * 64 + kk * 32 + l4 * 8);

    const f32x4 fz = {0.f, 0.f, 0.f, 0.f};
    f32x4 acc_o[4];
    #pragma unroll
    for (int n = 0; n < 4; ++n) acc_o[n] = fz;
    float tot = 0.f;

#define ASTAGE(s0_) do {                                                              \
    int lin0 = wave * 64;                                                             \
    int lin = lin0 + lane;                                                            \
    int r = lin >> 3, c = (lin & 7) ^ (r & 7);                                        \
    gll16(QKVb + (size_t)((s0_) + r) * 6144 + 4096 + h16 * 64 + c * 8, (char*)lK + lin0 * 16); \
    gll16(Vtb + (size_t)(h16 * 64 + r) * 1024 + (s0_) + c * 8,         (char*)lV + lin0 * 16); \
    lin0 += 256; lin = lin0 + lane; r = lin >> 3; c = (lin & 7) ^ (r & 7);            \
    gll16(QKVb + (size_t)((s0_) + r) * 6144 + 4096 + h16 * 64 + c * 8, (char*)lK + lin0 * 16); \
    gll16(Vtb + (size_t)(h16 * 64 + r) * 1024 + (s0_) + c * 8,         (char*)lV + lin0 * 16); \
    gll4(ksr + h16 * 1024 + (s0_) + lane, (char*)lks);                                \
} while (0)

// softmax in w'-domain: u = log2(1+2^zz); w' = u * sigmoid(SQUISH_U*u); threshold sinkp
#define SMAX(CAUSAL_) do {                                                            \
    _Pragma("unroll")                                                                 \
    for (int n = 0; n < 4; ++n) {                                                     \
        f32x4 ksv = *(const f32x4*)&lks[n * 16 + l4 * 4];                             \
        float w4[4];                                                                  \
        _Pragma("unroll")                                                             \
        for (int r = 0; r < 4; ++r) {                                                 \
            float zz = accs[n][r] * ksv[r];                                           \
            float t = __builtin_amdgcn_exp2f(zz);                                     \
            float u = __builtin_amdgcn_logf(1.f + t);                                 \
            if (CAUSAL_) {                                                            \
                int k_rel = n * 16 + l4 * 4 + r;                                      \
                u = (k_rel <= qrel) ? u : 0.f;                                        \
            }                                                                         \
            float g = __builtin_amdgcn_rcpf(1.f + __builtin_amdgcn_exp2f(-SQUISH_U * u)); \
            float w = u * g;                                                          \
            w = (w >= sinkp) ? w : 0.f;                                               \
            tot += w;                                                                 \
            w4[r] = w;                                                                \
        }                                                                             \
        unsigned pa = cvt_pk_bf16(w4[0], w4[1]);                                      \
        unsigned pb = cvt_pk_bf16(w4[2], w4[3]);                                      \
        int ch = (2 * n + (l4 >> 1)) ^ (l15 & 7);                                     \
        uint2 val; val.x = pa; val.y = pb;                                            \
        *(uint2*)&lP[wave][l15][ch * 8 + (l4 & 1) * 4] = val;                         \
    } } while (0)

    for (int kt = kb; kt < ke; ++kt) {
        int s0 = kt * 64;
        __syncthreads();
        ASTAGE(s0);
        asm volatile("s_waitcnt vmcnt(0)" ::: "memory");
        __syncthreads();

        // QK^T swapped: A = K (rows = keys), B = Q (cols = q)
        f32x4 accs[4];
        #pragma unroll
        for (int n = 0; n < 4; ++n) accs[n] = fz;
        #pragma unroll
        for (int kk = 0; kk < 2; ++kk) {
            bf16x8 bk[4];
            #pragma unroll
            for (int n = 0; n < 4; ++n) {
                int row = n * 16 + l15;
                int ch = (kk * 4 + l4) ^ (row & 7);
                bk[n] = *(const bf16x8*)&lK[row][ch << 3];
            }
            #pragma unroll
            for (int n = 0; n < 4; ++n)
                accs[n] = __builtin_amdgcn_mfma_f32_16x16x32_bf16(bk[n], aq[kk], accs[n], 0, 0, 0);
        }

        if (kt == qt) { SMAX(1); } else { SMAX(0); }   // mask only the diagonal tile

        // PV: A = P (rows = q), B = V^T (cols = d); per-wave private lP
        #pragma unroll
        for (int kk = 0; kk < 2; ++kk) {
            bf16x8 ap = *(const bf16x8*)&lP[wave][l15][((kk * 4 + l4) ^ (l15 & 7)) << 3];
            bf16x8 bv[4];
            #pragma unroll
            for (int n = 0; n < 4; ++n) {
                int row = n * 16 + l15;
                int ch = (kk * 4 + l4) ^ (row & 7);
                bv[n] = *(const bf16x8*)&lV[row][ch << 3];
            }
            #pragma unroll
            for (int n = 0; n < 4; ++n)
                acc_o[n] = __builtin_amdgcn_mfma_f32_16x16x32_bf16(ap, bv[n], acc_o[n], 0, 0, 0);
        }
    }
#undef ASTAGE
#undef SMAX

    tot += __shfl_xor(tot, 16, 64);
    tot += __shfl_xor(tot, 32, 64);

    if (single) {
        const float sinkeps = sinkp + 1e-6f * LOG2E;
        float tq[4];
        #pragma unroll
        for (int r = 0; r < 4; ++r) tq[r] = __shfl(tot, l4 * 4 + r, 64);
        #pragma unroll
        for (int r = 0; r < 4; ++r) {
            float inv = __builtin_amdgcn_rcpf(tq[r] + sinkeps);
            int trow = t0 + wave * 16 + l4 * 4 + r;
            #pragma unroll
            for (int n = 0; n < 4; ++n) {
                int d = n * 16 + l15;
                float val = (acc_o[n][r] + sinkp * lvn[d]) * inv;
                Ob[(size_t)trow * 4096 + h * 64 + d] = f2b(val);
            }
        }
    } else {
        // split rows (qt>=8): two blocks per row, each writes its own partial buffer
        float* Op = (kb == 0) ? Of0 : Of1;
        float* tp = (kb == 0) ? tot0 : tot1;
        if (lane < 16) tp[h * 512 + (t0 - 512) + wave * 16 + l15] = tot;
        #pragma unroll
        for (int r = 0; r < 4; ++r) {
            int pr = h * 512 + (t0 - 512) + wave * 16 + l4 * 4 + r;
            #pragma unroll
            for (int n = 0; n < 4; ++n)
                Op[(size_t)pr * 64 + n * 16 + l15] = acc_o[n][r];
        }
    }
}

// ---------- finalize split rows (w'-domain) ----------
__global__ __launch_bounds__(256) void norm_kernel(
    const float* __restrict__ Of0, const float* __restrict__ Of1,
    const float* __restrict__ tot0, const float* __restrict__ tot1,
    const float* __restrict__ sinks, const float* __restrict__ vnulls,
    short* __restrict__ Ob) {
    int gid = blockIdx.x * 256 + threadIdx.x;
    int i4 = gid * 4;
    int row = i4 >> 6;                   // h*512 + (t-512)
    int d0 = i4 & 63;
    int h = row >> 9;
    int t = 512 + (row & 511);
    float sinkp = sinks[h] * LOG2E;
    float inv = __builtin_amdgcn_rcpf(tot0[row] + tot1[row] + sinkp + 1e-6f * LOG2E);
    f32x4 a = *(const f32x4*)(Of0 + i4);
    f32x4 b = *(const f32x4*)(Of1 + i4);
    s16x4 rs;
    #pragma unroll
    for (int k = 0; k < 4; ++k)
        rs[k] = f2b((a[k] + b[k] + sinkp * vnulls[h * 64 + d0 + k]) * inv);
    *(s16x4*)(Ob + (size_t)t * 4096 + h * 64 + d0) = rs;
}

// ---------- launch ----------
extern "C" void kernel_launch(void* const* d_in, const int* in_sizes, int n_in,
                              void* d_out, int out_size, void* d_ws, size_t ws_size,
                              hipStream_t stream) {
    const float* X        = (const float*)d_in[0];
    const float* W_Q      = (const float*)d_in[1];
    const float* b_Q      = (const float*)d_in[2];
    const float* W_K      = (const float*)d_in[3];
    const float* b_K      = (const float*)d_in[4];
    const float* W_V      = (const float*)d_in[5];
    const float* b_V      = (const float*)d_in[6];
    const float* sinks    = (const float*)d_in[7];
    const float* v_nulls  = (const float*)d_in[8];
    const float* W_O      = (const float*)d_in[9];
    const float* W_O_bias = (const float*)d_in[10];
    float* out = (float*)d_out;
    char* ws = (char*)d_ws;

    short* Xb        = (short*)(ws + 0);          //  2 MB
    short* WbT       = (short*)(ws + 2097152);    // 12 MB
    short* WoT       = (short*)(ws + 14680064);   //  8 MB (x0.25)
    short* QKVb      = (short*)(ws + 23068672);   // 12 MB (V region unused)
    short* Vtb       = (short*)(ws + 35651584);   //  2 MB
    short* Ob        = (short*)(ws + 37748736);   //  8 MB
    float* ksr       = (float*)(ws + 46137344);   // 64 KB
    float* biasQKV   = (float*)(ws + 46202880);   // 24 KB
    float* Of0       = (float*)(ws + 50331648);   //  8.4 MB
    float* Of1       = (float*)(ws + 58720256);   //  8.4 MB
    float* tot0      = (float*)(ws + 67108864);   // 128 KB
    float* tot1      = (float*)(ws + 67239936);   // 128 KB

    prep_kernel<<<3864, 256, 0, stream>>>(X, W_Q, W_K, W_V, W_O, b_Q, b_K, b_V, W_O_bias,
                                          Xb, WbT, WoT, biasQKV, out);
    gemm_qkvf_kernel<<<dim3(48, 16), 256, 0, stream>>>(Xb, WbT, biasQKV, QKVb, Vtb, ksr,
                                                       1024, 6144, 1024);
    attn_kernel<<<dim3(64, 24), 256, 0, stream>>>(QKVb, Vtb, ksr, sinks, v_nulls, Ob,
                                                  Of0, Of1, tot0, tot1);
    norm_kernel<<<2048, 256, 0, stream>>>(Of0, Of1, tot0, tot1, sinks, v_nulls, Ob);
    gemm_op_kernel<<<dim3(8, 16, 4), 256, 0, stream>>>(Ob, WoT, out, 1024, 1024, 4096, 1024);
}